// Round 1
// baseline (139.361 us; speedup 1.0000x reference)
//
#include <hip/hip_runtime.h>
#include <math.h>

#define FD 76
#define FFD 5776
#define BD 16
#define CD 256
#define KD 50
#define AD 3

constexpr int BAFF = BD * AD * FFD; // 277248 cells

// ws layout (float offsets)
constexpr int SCALE_O = 0;              // [BAFF] matched scale (0 = unmatched)
constexpr int ACC_O   = BAFF;           // [6] lxy, lwh, lobj, lcls, l2, spare
constexpr int CNT_O   = BAFF + 6;       // [1] int match counter
constexpr int ZERO_N  = BAFF + 8;       // zeroed prefix length
constexpr int TXF_O   = ZERO_N;
constexpr int TYF_O   = TXF_O + BAFF;
constexpr int TWL_O   = TYF_O + BAFF;
constexpr int THL_O   = TWL_O + BAFF;
constexpr int CLS_O   = THL_O + BAFF;
constexpr int TBOX_O  = CLS_O + BAFF;   // [B*K*5] tx,ty,tw,th,valid
constexpr int PX_O    = TBOX_O + BD*KD*5;
constexpr int PY_O    = PX_O + BAFF;
constexpr int PW_O    = PY_O + BAFF;
constexpr int PH_O    = PW_O + BAFF;
constexpr int SOBJ_O  = PH_O + BAFF;
constexpr int LIST_O  = SOBJ_O + BAFF;  // [1024] int matched cell list

__device__ __forceinline__ float sigm(float x){ return 1.f/(1.f + expf(-x)); }
__device__ __forceinline__ float clg(float x){ return logf(fmaxf(x, 1e-12f)); }
__device__ __forceinline__ float bce(float o, float t){ return -(t*clg(o) + (1.f-t)*clg(1.f-o)); }

// ---------------- label kernel: 1 block, thread b loops k sequentially (last-wins) -----
__global__ void label_kernel(const float* __restrict__ labels, float* __restrict__ ws){
  const int b = threadIdx.x;
  if (b >= BD) return;
  const float AWH[9][2] = {{1.25f,1.625f},{2.f,3.75f},{4.125f,2.875f},
                           {3.75f,7.625f},{7.75f,5.625f},{7.375f,14.875f},
                           {14.5f,11.25f},{19.5f,24.75f},{46.625f,40.75f}};
  for (int k = 0; k < KD; ++k){
    const float* l = labels + (b*KD + k)*5;
    const float cls = l[0], x = l[1], y = l[2], w = l[3], h = l[4];
    const bool valid = (cls + x + y + w + h) > 0.f;
    const float tx = x*FD, ty = y*FD, tw = w*FD, th = h*FD;
    float* tb = ws + TBOX_O + (b*KD + k)*5;
    tb[0]=tx; tb[1]=ty; tb[2]=tw; tb[3]=th; tb[4] = valid ? 1.f : 0.f;
    const float ta = tw*th;
    float bestv = -1.f; int best = 0;
    #pragma unroll
    for (int n = 0; n < 9; ++n){
      const float mw = fminf(tw, AWH[n][0]), mh = fminf(th, AWH[n][1]);
      const float inter = (mw > 0.f && mh > 0.f) ? mw*mh : 0.f;
      const float iou = inter / (ta + AWH[n][0]*AWH[n][1] - inter);
      if (iou > bestv){ bestv = iou; best = n; }
    }
    const int bn = best % 3;
    const bool match = valid && (best < 3);
    const int ii = (int)tx;
    const int jj = (int)ty;
    if (match && ii >= 0 && ii < FD && jj >= 0 && jj < FD){
      const int cA = ((b*AD + bn)*FD + jj)*FD + ii;
      ws[SCALE_O + cA] = sqrtf(2.f - tw*th/(float)(FD*FD));   // always >= 1
      ws[TXF_O + cA] = tx - floorf(tx);
      ws[TYF_O + cA] = ty - floorf(ty);
      ws[TWL_O + cA] = logf(tw / AWH[bn][0] + 1e-16f);
      ws[THL_O + cA] = logf(th / AWH[bn][1] + 1e-16f);
      ws[CLS_O + cA] = cls;
    }
  }
}

// ---------------- conv kernel: 15 channels/cell, fused xy/wh losses -------------------
__global__ __launch_bounds__(256) void conv_kernel(const float* __restrict__ xin,
    const float* __restrict__ cw, const float* __restrict__ cb, float* __restrict__ ws){
  __shared__ float wT[256][16];
  const int tid = threadIdx.x;
  #pragma unroll
  for (int j = 0; j < 15; ++j){
    const int o = (j/5)*85 + (j%5);
    wT[tid][j] = cw[o*CD + tid];          // coalesced per j
  }
  wT[tid][15] = 0.f;
  __syncthreads();

  const int cell = blockIdx.x*256 + tid;  // grid = 92416/256 exactly
  const int b  = cell / FFD;
  const int hw = cell - b*FFD;
  const int hh = hw / FD;
  const int wc = hw - hh*FD;
  const float* xp = xin + ((size_t)b*CD)*FFD + hw;

  float4 A0 = {0,0,0,0}, A1 = {0,0,0,0}, A2 = {0,0,0,0}, A3 = {0,0,0,0};
  #pragma unroll 4
  for (int c = 0; c < CD; ++c){
    const float xv = xp[c*FFD];                               // coalesced across lanes
    const float4* wr = reinterpret_cast<const float4*>(&wT[c][0]); // uniform -> broadcast
    const float4 w0 = wr[0], w1 = wr[1], w2 = wr[2], w3 = wr[3];
    A0.x += xv*w0.x; A0.y += xv*w0.y; A0.z += xv*w0.z; A0.w += xv*w0.w;
    A1.x += xv*w1.x; A1.y += xv*w1.y; A1.z += xv*w1.z; A1.w += xv*w1.w;
    A2.x += xv*w2.x; A2.y += xv*w2.y; A2.z += xv*w2.z; A2.w += xv*w2.w;
    A3.x += xv*w3.x; A3.y += xv*w3.y; A3.z += xv*w3.z; A3.w += xv*w3.w;
  }
  const float acc[16] = {A0.x,A0.y,A0.z,A0.w, A1.x,A1.y,A1.z,A1.w,
                         A2.x,A2.y,A2.z,A2.w, A3.x,A3.y,A3.z,A3.w};

  const float MW[3][2] = {{1.25f,1.625f},{2.f,3.75f},{4.125f,2.875f}};
  float lxy = 0.f, lwh = 0.f, l2p = 0.f;
  #pragma unroll
  for (int a = 0; a < 3; ++a){
    const float v0 = acc[a*5+0] + cb[a*85+0];
    const float v1 = acc[a*5+1] + cb[a*85+1];
    const float v2 = acc[a*5+2] + cb[a*85+2];
    const float v3 = acc[a*5+3] + cb[a*85+3];
    const float v4 = acc[a*5+4] + cb[a*85+4];
    const float sx = sigm(v0), sy = sigm(v1), so = sigm(v4);
    const int cA = (b*AD + a)*FFD + hw;
    ws[PX_O + cA] = sx + (float)wc;
    ws[PY_O + cA] = sy + (float)hh;
    ws[PW_O + cA] = expf(v2)*MW[a][0];
    ws[PH_O + cA] = expf(v3)*MW[a][1];
    ws[SOBJ_O + cA] = so;
    const float sc = ws[SCALE_O + cA];
    if (sc > 0.f){                        // matched cell: fused xy/wh + l2 losses
      const float txf = ws[TXF_O + cA], tyf = ws[TYF_O + cA];
      const float twl = ws[TWL_O + cA], thl = ws[THL_O + cA];
      lxy += sc*sc*(bce(sx, txf) + bce(sy, tyf));
      l2p += (sx-txf)*(sx-txf) + (sy-tyf)*(sy-tyf);
      const float d0 = v2 - twl, d1 = v3 - thl;
      lwh += 0.5f*sc*sc*(d0*d0 + d1*d1);
      l2p += sc*sc*(d0*d0 + d1*d1);
      const int pos = atomicAdd((int*)ws + CNT_O, 1);
      if (pos < 1024) ((int*)ws)[LIST_O + pos] = cA;
    }
  }
  // block reduce the three partials into global accumulators
  float* sm = &wT[0][0];
  #pragma unroll
  for (int r = 0; r < 3; ++r){
    const float v = (r == 0) ? lxy : (r == 1) ? lwh : l2p;
    __syncthreads();
    sm[tid] = v;
    __syncthreads();
    for (int s = 128; s > 0; s >>= 1){
      if (tid < s) sm[tid] += sm[tid + s];
      __syncthreads();
    }
    if (tid == 0 && sm[0] != 0.f)
      atomicAdd(ws + ACC_O + ((r == 0) ? 0 : (r == 1) ? 1 : 4), sm[0]);
  }
}

// ---------------- cls kernel: 80 channels at matched cells only -----------------------
__global__ __launch_bounds__(128) void cls_kernel(const float* __restrict__ xin,
    const float* __restrict__ cw, const float* __restrict__ cb, float* __restrict__ ws){
  const int cnt = ((const int*)ws)[CNT_O];
  if ((int)blockIdx.x >= cnt) return;
  const int cA = ((const int*)ws)[LIST_O + blockIdx.x];
  const int b   = cA / (AD*FFD);
  const int rem = cA - b*AD*FFD;
  const int a   = rem / FFD;
  const int hw  = rem - a*FFD;
  __shared__ float xs[256];
  __shared__ float sm[128];
  const int tid = threadIdx.x;
  const float* xb = xin + ((size_t)b*CD)*FFD + hw;
  xs[tid]       = xb[(size_t)tid*FFD];
  xs[tid + 128] = xb[(size_t)(tid + 128)*FFD];
  __syncthreads();
  float lcls = 0.f, l2p = 0.f;
  if (tid < 80){
    const int o = a*85 + 5 + tid;
    const float* wr = cw + o*CD;
    float s = 0.f;
    #pragma unroll 8
    for (int c = 0; c < CD; ++c) s += xs[c]*wr[c];
    const float e = sigm(s + cb[o]);
    const int cls = (int)ws[CLS_O + cA];
    const float t = (tid == cls) ? 1.f : 0.f;
    lcls = bce(e, t);
    l2p  = (e - t)*(e - t);
  }
  sm[tid] = lcls; __syncthreads();
  for (int s2 = 64; s2 > 0; s2 >>= 1){ if (tid < s2) sm[tid] += sm[tid+s2]; __syncthreads(); }
  if (tid == 0) atomicAdd(ws + ACC_O + 3, sm[0]);
  __syncthreads();
  sm[tid] = l2p; __syncthreads();
  for (int s2 = 64; s2 > 0; s2 >>= 1){ if (tid < s2) sm[tid] += sm[tid+s2]; __syncthreads(); }
  if (tid == 0) atomicAdd(ws + ACC_O + 4, sm[0]);
}

// ---------------- obj kernel: ignore mask via max-IoU over 50 targets -----------------
__global__ __launch_bounds__(256) void obj_kernel(float* __restrict__ ws){
  __shared__ float sm[256];
  const int tid = threadIdx.x;
  const int cA = blockIdx.x*256 + tid;   // grid = 277248/256 exactly
  const int b = cA / (AD*FFD);
  const float px = ws[PX_O + cA], py = ws[PY_O + cA];
  const float pw = ws[PW_O + cA], ph = ws[PH_O + cA];
  const float so = ws[SOBJ_O + cA];
  const bool matched = ws[SCALE_O + cA] > 0.f;
  const float* tb = ws + TBOX_O + b*KD*5;
  const float px0 = px - pw*0.5f, px1 = px + pw*0.5f;
  const float py0 = py - ph*0.5f, py1 = py + ph*0.5f;
  const float parea = pw*ph;
  float mx = 0.f;
  for (int k = 0; k < KD; ++k){
    const float tx = tb[k*5+0], ty = tb[k*5+1];
    const float tw = tb[k*5+2], th = tb[k*5+3], vl = tb[k*5+4];
    const float lx = fmaxf(px0, tx - tw*0.5f), rx = fminf(px1, tx + tw*0.5f);
    const float ly = fmaxf(py0, ty - th*0.5f), ry = fminf(py1, ty + th*0.5f);
    float inter = (rx - lx)*(ry - ly);
    inter = (lx < rx && ly < ry) ? inter : 0.f;
    float iou = inter / (parea + tw*th - inter);
    iou = (vl > 0.f) ? iou : 0.f;
    mx = fmaxf(mx, iou);
  }
  const bool ignore = mx > 0.7f;
  float lobj = 0.f, l2p = 0.f;
  if (matched){ lobj = -clg(so); l2p = (so - 1.f)*(so - 1.f); }
  else if (!ignore){ lobj = -clg(1.f - so); l2p = so*so; }
  sm[tid] = lobj; __syncthreads();
  for (int s = 128; s > 0; s >>= 1){ if (tid < s) sm[tid] += sm[tid+s]; __syncthreads(); }
  if (tid == 0) atomicAdd(ws + ACC_O + 2, sm[0]);
  __syncthreads();
  sm[tid] = l2p; __syncthreads();
  for (int s = 128; s > 0; s >>= 1){ if (tid < s) sm[tid] += sm[tid+s]; __syncthreads(); }
  if (tid == 0) atomicAdd(ws + ACC_O + 4, sm[0]);
}

// ---------------- finalize ------------------------------------------------------------
__global__ void fin_kernel(const float* __restrict__ ws, float* __restrict__ out){
  const float lxy = ws[ACC_O+0], lwh = ws[ACC_O+1], lobj = ws[ACC_O+2];
  const float lcls = ws[ACC_O+3], l2 = ws[ACC_O+4];
  out[0] = lxy + lwh + lobj + lcls;
  out[1] = lxy; out[2] = lwh; out[3] = lobj; out[4] = lcls; out[5] = l2;
}

extern "C" void kernel_launch(void* const* d_in, const int* in_sizes, int n_in,
                              void* d_out, int out_size, void* d_ws, size_t ws_size,
                              hipStream_t stream){
  const float* xin    = (const float*)d_in[0];
  const float* labels = (const float*)d_in[1];
  const float* cw     = (const float*)d_in[2];
  const float* cb     = (const float*)d_in[3];
  float* out = (float*)d_out;
  float* ws  = (float*)d_ws;

  hipMemsetAsync(ws, 0, (size_t)ZERO_N*sizeof(float), stream);
  label_kernel<<<1, 64, 0, stream>>>(labels, ws);
  conv_kernel<<<BD*FFD/256, 256, 0, stream>>>(xin, cw, cb, ws);
  cls_kernel<<<1024, 128, 0, stream>>>(xin, cw, cb, ws);
  obj_kernel<<<BAFF/256, 256, 0, stream>>>(ws);
  fin_kernel<<<1, 1, 0, stream>>>(ws, out);
}

// Round 2
// 109.768 us; speedup vs baseline: 1.2696x; 1.2696x over previous
//
#include <hip/hip_runtime.h>
#include <math.h>

#define FD 76
#define FFD 5776
#define BD 16
#define CD 256
#define KD 50
#define AD 3

constexpr int NCELL = BD * FFD;          // 92416
constexpr int BAFF  = BD * AD * FFD;     // 277248
constexpr int NBLK  = NCELL / 64;        // 1444 blocks for fused kernel

// ws layout (float offsets)
constexpr int SCALE_O = 0;               // [BAFF] matched scale (0 = unmatched)
constexpr int ACC_O   = BAFF;            // [8]: [3]=lcls atomic, [4]=l2cls atomic
constexpr int CNT_O   = BAFF + 8;        // [1] int match counter
constexpr int ZERO_N  = BAFF + 16;       // zeroed prefix length
constexpr int TXF_O   = ZERO_N;
constexpr int TYF_O   = TXF_O + BAFF;
constexpr int TWL_O   = TYF_O + BAFF;
constexpr int THL_O   = TWL_O + BAFF;
constexpr int CLS_O   = THL_O + BAFF;
constexpr int TBOX_O  = CLS_O + BAFF;    // [B*K*5] tx,ty,tw,th,valid
constexpr int LIST_O  = TBOX_O + BD*KD*5;// [1024] int matched cell list
constexpr int BLK_O   = LIST_O + 1024;   // [NBLK*4] per-block loss partials

__device__ __forceinline__ float sigm(float x){ return 1.f/(1.f + expf(-x)); }
__device__ __forceinline__ float clg(float x){ return logf(fmaxf(x, 1e-12f)); }
__device__ __forceinline__ float bce(float o, float t){ return -(t*clg(o) + (1.f-t)*clg(1.f-o)); }

// ---------------- label kernel: 1 block, thread b loops k sequentially (last-wins) ----
__global__ void label_kernel(const float* __restrict__ labels, float* __restrict__ ws){
  const int b = threadIdx.x;
  if (b >= BD) return;
  const float AWH[9][2] = {{1.25f,1.625f},{2.f,3.75f},{4.125f,2.875f},
                           {3.75f,7.625f},{7.75f,5.625f},{7.375f,14.875f},
                           {14.5f,11.25f},{19.5f,24.75f},{46.625f,40.75f}};
  for (int k = 0; k < KD; ++k){
    const float* l = labels + (b*KD + k)*5;
    const float cls = l[0], x = l[1], y = l[2], w = l[3], h = l[4];
    const bool valid = (cls + x + y + w + h) > 0.f;
    const float tx = x*FD, ty = y*FD, tw = w*FD, th = h*FD;
    float* tb = ws + TBOX_O + (b*KD + k)*5;
    tb[0]=tx; tb[1]=ty; tb[2]=tw; tb[3]=th; tb[4] = valid ? 1.f : 0.f;
    const float ta = tw*th;
    float bestv = -1.f; int best = 0;
    #pragma unroll
    for (int n = 0; n < 9; ++n){
      const float mw = fminf(tw, AWH[n][0]), mh = fminf(th, AWH[n][1]);
      const float inter = (mw > 0.f && mh > 0.f) ? mw*mh : 0.f;
      const float iou = inter / (ta + AWH[n][0]*AWH[n][1] - inter);
      if (iou > bestv){ bestv = iou; best = n; }
    }
    const int bn = best % 3;
    const bool match = valid && (best < 3);
    const int ii = (int)tx;
    const int jj = (int)ty;
    if (match && ii >= 0 && ii < FD && jj >= 0 && jj < FD){
      const int cA = ((b*AD + bn)*FD + jj)*FD + ii;
      ws[SCALE_O + cA] = sqrtf(2.f - tw*th/(float)(FD*FD));   // always >= 1
      ws[TXF_O + cA] = tx - floorf(tx);
      ws[TYF_O + cA] = ty - floorf(ty);
      ws[TWL_O + cA] = logf(tw / AWH[bn][0] + 1e-16f);
      ws[THL_O + cA] = logf(th / AWH[bn][1] + 1e-16f);
      ws[CLS_O + cA] = cls;
    }
  }
}

// ---------------- fused conv + epilogue + obj kernel ----------------------------------
// 1444 blocks x 256 threads. Block = 64 cells; wave w accumulates channels [w*64,w*64+64).
__global__ __launch_bounds__(256) void fused_kernel(const float* __restrict__ xin,
    const float* __restrict__ cw, const float* __restrict__ cb, float* __restrict__ ws){
  __shared__ __align__(16) float lds[4352];   // W: [256][16]; comb: [4][64][17]
  const int tid  = threadIdx.x;
  const int w    = tid >> 6;
  const int lane = tid & 63;

  // stage 15 needed W rows: lds[c*16 + j] = cw[o(j)*256 + c]
  #pragma unroll
  for (int j = 0; j < 15; ++j){
    const int o = (j/5)*85 + (j%5);
    lds[tid*16 + j] = cw[o*CD + tid];       // coalesced per j
  }
  lds[tid*16 + 15] = 0.f;
  __syncthreads();

  const int cell = blockIdx.x*64 + lane;
  const int b  = cell / FFD;
  const int hw = cell - b*FFD;
  const float* xp = xin + ((size_t)b*CD)*FFD + hw;

  float4 A0 = {0,0,0,0}, A1 = {0,0,0,0}, A2 = {0,0,0,0}, A3 = {0,0,0,0};
  const int cbase = w*64;
  #pragma unroll
  for (int ch = 0; ch < 4; ++ch){
    float xr[16];
    #pragma unroll
    for (int i = 0; i < 16; ++i)            // 16 independent loads in flight
      xr[i] = xp[(size_t)(cbase + ch*16 + i)*FFD];
    #pragma unroll
    for (int i = 0; i < 16; ++i){
      const float4* wr = reinterpret_cast<const float4*>(&lds[(cbase + ch*16 + i)*16]);
      const float4 w0 = wr[0], w1 = wr[1], w2 = wr[2], w3 = wr[3];
      const float xv = xr[i];
      A0.x += xv*w0.x; A0.y += xv*w0.y; A0.z += xv*w0.z; A0.w += xv*w0.w;
      A1.x += xv*w1.x; A1.y += xv*w1.y; A1.z += xv*w1.z; A1.w += xv*w1.w;
      A2.x += xv*w2.x; A2.y += xv*w2.y; A2.z += xv*w2.z; A2.w += xv*w2.w;
      A3.x += xv*w3.x; A3.y += xv*w3.y; A3.z += xv*w3.z;
    }
  }

  // combine partial sums across the 4 waves: comb[w][cell][j], stride 17 (conflict-free)
  __syncthreads();                          // everyone done reading W region
  {
    float acc[15] = {A0.x,A0.y,A0.z,A0.w, A1.x,A1.y,A1.z,A1.w,
                     A2.x,A2.y,A2.z,A2.w, A3.x,A3.y,A3.z};
    float* cmb = &lds[w*1088 + lane*17];
    #pragma unroll
    for (int j = 0; j < 15; ++j) cmb[j] = acc[j];
  }
  __syncthreads();

  // epilogue: 192 threads = 64 cells x 3 anchors
  const float MW[3][2] = {{1.25f,1.625f},{2.f,3.75f},{4.125f,2.875f}};
  float lxy = 0.f, lwh = 0.f, lobj = 0.f, l2p = 0.f;
  const int a = tid >> 6;                   // reuse w as anchor index
  if (a < 3){
    const int cellE = tid & 63;
    float v[5];
    #pragma unroll
    for (int j = 0; j < 5; ++j){
      const int jo = a*5 + j;
      v[j] = lds[0*1088 + cellE*17 + jo] + lds[1*1088 + cellE*17 + jo]
           + lds[2*1088 + cellE*17 + jo] + lds[3*1088 + cellE*17 + jo]
           + cb[a*85 + j];
    }
    const int cellG = blockIdx.x*64 + cellE;
    const int bE  = cellG / FFD;
    const int hwE = cellG - bE*FFD;
    const int hhE = hwE / FD;
    const int wcE = hwE - hhE*FD;
    const float sx = sigm(v[0]), sy = sigm(v[1]), so = sigm(v[4]);
    const float px = sx + (float)wcE, py = sy + (float)hhE;
    const float pw = expf(v[2])*MW[a][0], ph = expf(v[3])*MW[a][1];
    const int cA = (bE*AD + a)*FFD + hwE;
    const float sc = ws[SCALE_O + cA];
    const bool matched = sc > 0.f;
    if (matched){
      const float txf = ws[TXF_O + cA], tyf = ws[TYF_O + cA];
      const float twl = ws[TWL_O + cA], thl = ws[THL_O + cA];
      lxy = sc*sc*(bce(sx, txf) + bce(sy, tyf));
      l2p = (sx-txf)*(sx-txf) + (sy-tyf)*(sy-tyf);
      const float d0 = v[2] - twl, d1 = v[3] - thl;
      lwh = 0.5f*sc*sc*(d0*d0 + d1*d1);
      l2p += sc*sc*(d0*d0 + d1*d1);
      const int pos = atomicAdd((int*)ws + CNT_O, 1);
      if (pos < 1024) ((int*)ws)[LIST_O + pos] = cA;
    }
    // ignore mask: max IoU of this cell's pred box vs the 50 targets of batch bE
    const float* tb = ws + TBOX_O + bE*KD*5;
    const float px0 = px - pw*0.5f, px1 = px + pw*0.5f;
    const float py0 = py - ph*0.5f, py1 = py + ph*0.5f;
    const float parea = pw*ph;
    float mx = 0.f;
    for (int k = 0; k < KD; ++k){
      const float tx = tb[k*5+0], ty = tb[k*5+1];
      const float tw = tb[k*5+2], th = tb[k*5+3], vl = tb[k*5+4];
      const float lx = fmaxf(px0, tx - tw*0.5f), rx = fminf(px1, tx + tw*0.5f);
      const float ly = fmaxf(py0, ty - th*0.5f), ry = fminf(py1, ty + th*0.5f);
      float inter = (rx - lx)*(ry - ly);
      inter = (lx < rx && ly < ry) ? inter : 0.f;
      float iou = inter / (parea + tw*th - inter);
      iou = (vl > 0.f) ? iou : 0.f;
      mx = fmaxf(mx, iou);
    }
    if (matched){ lobj = -clg(so); l2p += (so - 1.f)*(so - 1.f); }
    else if (!(mx > 0.7f)){ lobj = -clg(1.f - so); l2p += so*so; }
  }

  // in-wave shuffle reduce, then cross-wave via LDS, one deterministic block partial
  #pragma unroll
  for (int o = 32; o > 0; o >>= 1){
    lxy  += __shfl_down(lxy,  o, 64);
    lwh  += __shfl_down(lwh,  o, 64);
    lobj += __shfl_down(lobj, o, 64);
    l2p  += __shfl_down(l2p,  o, 64);
  }
  __syncthreads();                          // done reading comb region
  if (lane == 0){
    lds[w*4+0] = lxy; lds[w*4+1] = lwh; lds[w*4+2] = lobj; lds[w*4+3] = l2p;
  }
  __syncthreads();
  if (tid < 4){
    ws[BLK_O + blockIdx.x*4 + tid] =
      lds[0*4+tid] + lds[1*4+tid] + lds[2*4+tid] + lds[3*4+tid];
  }
}

// ---------------- cls kernel: 80 channels at matched cells only -----------------------
__global__ __launch_bounds__(128) void cls_kernel(const float* __restrict__ xin,
    const float* __restrict__ cw, const float* __restrict__ cb, float* __restrict__ ws){
  const int cnt = ((const int*)ws)[CNT_O];
  if ((int)blockIdx.x >= cnt) return;
  const int cA = ((const int*)ws)[LIST_O + blockIdx.x];
  const int b   = cA / (AD*FFD);
  const int rem = cA - b*AD*FFD;
  const int a   = rem / FFD;
  const int hw  = rem - a*FFD;
  __shared__ float xs[256];
  __shared__ float sm[128];
  const int tid = threadIdx.x;
  const float* xb = xin + ((size_t)b*CD)*FFD + hw;
  xs[tid]       = xb[(size_t)tid*FFD];
  xs[tid + 128] = xb[(size_t)(tid + 128)*FFD];
  __syncthreads();
  float lcls = 0.f, l2p = 0.f;
  if (tid < 80){
    const int o = a*85 + 5 + tid;
    const float* wr = cw + o*CD;
    float s = 0.f;
    #pragma unroll 8
    for (int c = 0; c < CD; ++c) s += xs[c]*wr[c];
    const float e = sigm(s + cb[o]);
    const int cls = (int)ws[CLS_O + cA];
    const float t = (tid == cls) ? 1.f : 0.f;
    lcls = bce(e, t);
    l2p  = (e - t)*(e - t);
  }
  sm[tid] = lcls; __syncthreads();
  for (int s2 = 64; s2 > 0; s2 >>= 1){ if (tid < s2) sm[tid] += sm[tid+s2]; __syncthreads(); }
  if (tid == 0) atomicAdd(ws + ACC_O + 3, sm[0]);
  __syncthreads();
  sm[tid] = l2p; __syncthreads();
  for (int s2 = 64; s2 > 0; s2 >>= 1){ if (tid < s2) sm[tid] += sm[tid+s2]; __syncthreads(); }
  if (tid == 0) atomicAdd(ws + ACC_O + 4, sm[0]);
}

// ---------------- finalize: sum 1444 block partials + cls atomics ---------------------
__global__ __launch_bounds__(256) void fin_kernel(const float* __restrict__ ws,
                                                  float* __restrict__ out){
  __shared__ float sm[256];
  const int tid = threadIdx.x;
  float p[4] = {0,0,0,0};
  for (int i = tid; i < NBLK; i += 256){
    p[0] += ws[BLK_O + i*4 + 0];
    p[1] += ws[BLK_O + i*4 + 1];
    p[2] += ws[BLK_O + i*4 + 2];
    p[3] += ws[BLK_O + i*4 + 3];
  }
  float tot[4];
  #pragma unroll
  for (int r = 0; r < 4; ++r){
    __syncthreads();
    sm[tid] = p[r];
    __syncthreads();
    for (int s = 128; s > 0; s >>= 1){
      if (tid < s) sm[tid] += sm[tid + s];
      __syncthreads();
    }
    tot[r] = sm[0];
  }
  if (tid == 0){
    const float lxy = tot[0], lwh = tot[1], lobj = tot[2];
    const float lcls = ws[ACC_O+3];
    const float l2   = tot[3] + ws[ACC_O+4];
    out[0] = lxy + lwh + lobj + lcls;
    out[1] = lxy; out[2] = lwh; out[3] = lobj; out[4] = lcls; out[5] = l2;
  }
}

extern "C" void kernel_launch(void* const* d_in, const int* in_sizes, int n_in,
                              void* d_out, int out_size, void* d_ws, size_t ws_size,
                              hipStream_t stream){
  const float* xin    = (const float*)d_in[0];
  const float* labels = (const float*)d_in[1];
  const float* cw     = (const float*)d_in[2];
  const float* cb     = (const float*)d_in[3];
  float* out = (float*)d_out;
  float* ws  = (float*)d_ws;

  hipMemsetAsync(ws, 0, (size_t)ZERO_N*sizeof(float), stream);
  label_kernel<<<1, 64, 0, stream>>>(labels, ws);
  fused_kernel<<<NBLK, 256, 0, stream>>>(xin, cw, cb, ws);
  cls_kernel<<<800, 128, 0, stream>>>(xin, cw, cb, ws);
  fin_kernel<<<1, 256, 0, stream>>>(ws, out);
}

// Round 3
// 52.989 us; speedup vs baseline: 2.6300x; 2.0715x over previous
//
#include <hip/hip_runtime.h>
#include <math.h>

#define FD 76
#define FFD 5776
#define BD 16
#define CD 256
#define KD 50
#define AD 3

typedef float f32x2 __attribute__((ext_vector_type(2)));
typedef float f32x4 __attribute__((ext_vector_type(4)));

constexpr int NCELL = BD * FFD;          // 92416
constexpr int CBLK  = 128;               // cells per block
constexpr int NBLK  = NCELL / CBLK;      // 722

// ws layout (float offsets)
constexpr int ACC_O  = 0;                // [8]: [3]=lcls, [4]=l2cls (cls-kernel atomics)
constexpr int CNT_O  = 8;                // [1] int match counter
constexpr int LIST_O = 16;               // [1024][2] ints (cA, cls)
constexpr int TREC_O = 2064;             // [800][16] per-(b,k) records (16B aligned)
constexpr int BLK_O  = TREC_O + 800*16;  // [NBLK*4] per-block loss partials

__device__ __forceinline__ float sigm(float x){ return 1.f/(1.f + expf(-x)); }
__device__ __forceinline__ float clg(float x){ return logf(fmaxf(x, 1e-12f)); }
__device__ __forceinline__ float bce(float o, float t){ return -(t*clg(o) + (1.f-t)*clg(1.f-o)); }

// record layout [16]: 0:tx0 1:tx1 2:ty0 3:ty1 4:c7(0.7*ta) 5:code 6:txf 7:tyf
//                     8:twl 9:thl 10:scale 11:cls 12..15 pad
__global__ __launch_bounds__(256) void label_kernel(const float* __restrict__ labels,
                                                    float* __restrict__ ws){
  const int it = blockIdx.x*256 + threadIdx.x;
  if (blockIdx.x == 0 && threadIdx.x < 9){
    if (threadIdx.x < 8) ws[ACC_O + threadIdx.x] = 0.f;
    else ((int*)ws)[CNT_O] = 0;
  }
  if (it >= BD*KD) return;
  const float AWH[9][2] = {{1.25f,1.625f},{2.f,3.75f},{4.125f,2.875f},
                           {3.75f,7.625f},{7.75f,5.625f},{7.375f,14.875f},
                           {14.5f,11.25f},{19.5f,24.75f},{46.625f,40.75f}};
  const float* l = labels + it*5;
  const float cls = l[0], x = l[1], y = l[2], w = l[3], h = l[4];
  const bool valid = (cls + x + y + w + h) > 0.f;
  const float tx = x*FD, ty = y*FD, tw = w*FD, th = h*FD;
  const float ta = tw*th;
  float bestv = -1.f; int best = 0;
  #pragma unroll
  for (int n = 0; n < 9; ++n){
    const float mw = fminf(tw, AWH[n][0]), mh = fminf(th, AWH[n][1]);
    const float inter = (mw > 0.f && mh > 0.f) ? mw*mh : 0.f;
    const float iou = inter / (ta + AWH[n][0]*AWH[n][1] - inter);
    if (iou > bestv){ bestv = iou; best = n; }
  }
  const int bn = best % 3;
  const bool match = valid && (best < 3);
  const int ii = (int)tx, jj = (int)ty;
  const bool inb = (ii >= 0 && ii < FD && jj >= 0 && jj < FD);
  const float code = (match && inb) ? (float)(bn*FFD + jj*FD + ii) : -1.f;
  const float aw0 = (bn==0)?1.25f:((bn==1)?2.f:4.125f);
  const float aw1 = (bn==0)?1.625f:((bn==1)?3.75f:2.875f);
  float* r = ws + TREC_O + it*16;
  f32x4 r0 = {tx - tw*0.5f, tx + tw*0.5f, ty - th*0.5f, ty + th*0.5f};
  f32x4 r1 = {valid ? 0.7f*ta : 1e30f, code, tx - floorf(tx), ty - floorf(ty)};
  f32x4 r2 = {logf(tw/aw0 + 1e-16f), logf(th/aw1 + 1e-16f),
              sqrtf(2.f - ta/(float)(FD*FD)), cls};
  f32x4 r3 = {0.f, 0.f, 0.f, 0.f};
  *(f32x4*)(r+0) = r0; *(f32x4*)(r+4) = r1; *(f32x4*)(r+8) = r2; *(f32x4*)(r+12) = r3;
}

// ---------------- fused conv + epilogue (match resolve + IoU + losses) ----------------
// 722 blocks x 256 threads. Block = 128 cells (2/lane); wave wv does 64 channels.
__global__ __launch_bounds__(256) void fused_kernel(const float* __restrict__ xin,
    const float* __restrict__ cw, const float* __restrict__ cb, float* __restrict__ ws){
  __shared__ __align__(16) float lds[1600 + 7680]; // trec[2][50][16] | wT[256][16] / comb[4][15][128]
  float* trec  = lds;
  float* phase = lds + 1600;
  const int tid  = threadIdx.x;
  const int wv   = tid >> 6;
  const int lane = tid & 63;

  const int cell0blk = blockIdx.x*CBLK;
  const int bB0 = cell0blk / FFD;
  const int bB1 = (bB0 + 1 < BD) ? bB0 + 1 : bB0;

  // stage 2 batches of records (400 f32x4)
  {
    const f32x4* src = (const f32x4*)(ws + TREC_O);
    f32x4* dst = (f32x4*)trec;
    int q = tid;
    dst[q] = (q < 200) ? src[bB0*200 + q] : src[bB1*200 + q - 200];
    q = tid + 256;
    if (q < 400) dst[q] = src[bB1*200 + q - 200];
  }
  // stage 15 W rows: wT[c*16+j] = cw[o(j)*256+c]
  #pragma unroll
  for (int j = 0; j < 15; ++j){
    const int o = (j/5)*85 + (j%5);
    phase[tid*16 + j] = cw[o*CD + tid];
  }
  phase[tid*16 + 15] = 0.f;
  __syncthreads();

  // ---- conv: lane owns cells (cell0blk + 2*lane, +1); wave owns 64 channels ----
  const int cellP = cell0blk + 2*lane;
  const int bC  = cellP / FFD;
  const int hwC = cellP - bC*FFD;
  const float* xp = xin + ((size_t)bC*CD + wv*64)*FFD + hwC;

  f32x2 acc[15];
  #pragma unroll
  for (int j = 0; j < 15; ++j) acc[j] = (f32x2){0.f, 0.f};

  f32x2 xr[16], xn[16];
  #pragma unroll
  for (int i = 0; i < 16; ++i) xr[i] = *(const f32x2*)(xp + (size_t)i*FFD);
  #pragma unroll
  for (int cc = 0; cc < 4; ++cc){
    if (cc < 3){
      #pragma unroll
      for (int i = 0; i < 16; ++i)
        xn[i] = *(const f32x2*)(xp + (size_t)((cc+1)*16 + i)*FFD);
    }
    #pragma unroll
    for (int i = 0; i < 16; ++i){
      const int c = wv*64 + cc*16 + i;
      const f32x4* wr = (const f32x4*)&phase[c*16];
      const f32x4 w0 = wr[0], w1 = wr[1], w2 = wr[2], w3 = wr[3];
      const f32x2 xv = xr[i];
      acc[0]  += w0.x*xv; acc[1]  += w0.y*xv; acc[2]  += w0.z*xv; acc[3]  += w0.w*xv;
      acc[4]  += w1.x*xv; acc[5]  += w1.y*xv; acc[6]  += w1.z*xv; acc[7]  += w1.w*xv;
      acc[8]  += w2.x*xv; acc[9]  += w2.y*xv; acc[10] += w2.z*xv; acc[11] += w2.w*xv;
      acc[12] += w3.x*xv; acc[13] += w3.y*xv; acc[14] += w3.z*xv;
    }
    if (cc < 3){
      #pragma unroll
      for (int i = 0; i < 16; ++i) xr[i] = xn[i];
    }
  }

  __syncthreads();                         // done reading wT
  // comb[wv][j][cell], j-major stride 128
  #pragma unroll
  for (int j = 0; j < 15; ++j)
    *(f32x2*)&phase[wv*1920 + j*128 + 2*lane] = acc[j];
  __syncthreads();

  // ---- epilogue: 384 (cell,anchor) items; threads 0..191 take item pair (2t,2t+1) ----
  float lxy = 0.f, lwh = 0.f, lobj = 0.f, l2p = 0.f;
  if (tid < 192){
    const int it0 = 2*tid;
    const int a = it0 >> 7;
    const int cell0 = it0 & 127, cell1 = cell0 + 1;
    const float mw0 = (a==0)?1.25f:((a==1)?2.f:4.125f);
    const float mw1 = (a==0)?1.625f:((a==1)?3.75f:2.875f);
    float v0[5], v1[5];
    #pragma unroll
    for (int jj = 0; jj < 5; ++jj){
      const float bias = cb[a*85 + jj];
      float s0 = bias, s1 = bias;
      #pragma unroll
      for (int w2 = 0; w2 < 4; ++w2){
        const f32x2 q = *(const f32x2*)&phase[w2*1920 + (a*5+jj)*128 + cell0];
        s0 += q.x; s1 += q.y;
      }
      v0[jj] = s0; v1[jj] = s1;
    }
    const int g0 = cell0blk + cell0;
    const int bb = g0 / FFD;
    const int hw0 = g0 - bb*FFD,  hw1 = hw0 + 1;
    const int hh0 = hw0 / FD, wc0 = hw0 - hh0*FD;
    const int hh1 = hw1 / FD, wc1 = hw1 - hh1*FD;

    const float sx0 = sigm(v0[0]), sy0 = sigm(v0[1]), so0 = sigm(v0[4]);
    const float sx1 = sigm(v1[0]), sy1 = sigm(v1[1]), so1 = sigm(v1[4]);
    const float pw0 = expf(v0[2])*mw0, ph0 = expf(v0[3])*mw1;
    const float pw1 = expf(v1[2])*mw0, ph1 = expf(v1[3])*mw1;
    const float px0a = sx0 + wc0 - pw0*0.5f, px0b = sx0 + wc0 + pw0*0.5f;
    const float py0a = sy0 + hh0 - ph0*0.5f, py0b = sy0 + hh0 + ph0*0.5f;
    const float px1a = sx1 + wc1 - pw1*0.5f, px1b = sx1 + wc1 + pw1*0.5f;
    const float py1a = sy1 + hh1 - ph1*0.5f, py1b = sy1 + hh1 + ph1*0.5f;
    const float s7_0 = 0.7f*pw0*ph0, s7_1 = 0.7f*pw1*ph1;
    const float code0 = (float)(a*FFD + hw0), code1 = (float)(a*FFD + hw1);

    const float* rb = trec + ((bb == bB0) ? 0 : 800);
    float mx0 = -1e30f, mx1 = -1e30f;
    int ks0 = -1, ks1 = -1;
    for (int k = 0; k < KD; ++k){
      const f32x4 rA = *(const f32x4*)&rb[k*16];      // tx0 tx1 ty0 ty1
      const f32x2 rB = *(const f32x2*)&rb[k*16 + 4];  // c7, code
      {
        const float dx = fminf(px0b, rA.y) - fmaxf(px0a, rA.x);
        const float dy = fminf(py0b, rA.w) - fmaxf(py0a, rA.z);
        const float inter = fmaxf(dx, 0.f)*fmaxf(dy, 0.f);
        mx0 = fmaxf(mx0, 1.7f*inter - rB.x);
        ks0 = (rB.y == code0) ? k : ks0;
      }
      {
        const float dx = fminf(px1b, rA.y) - fmaxf(px1a, rA.x);
        const float dy = fminf(py1b, rA.w) - fmaxf(py1a, rA.z);
        const float inter = fmaxf(dx, 0.f)*fmaxf(dy, 0.f);
        mx1 = fmaxf(mx1, 1.7f*inter - rB.x);
        ks1 = (rB.y == code1) ? k : ks1;
      }
    }
    // item 0
    if (ks0 >= 0){
      const f32x2 p0 = *(const f32x2*)&rb[ks0*16 + 6];
      const f32x4 p1 = *(const f32x4*)&rb[ks0*16 + 8];
      const float sc = p1.z, sc2 = sc*sc;
      lxy += sc2*(bce(sx0, p0.x) + bce(sy0, p0.y));
      l2p += (sx0-p0.x)*(sx0-p0.x) + (sy0-p0.y)*(sy0-p0.y);
      const float d0 = v0[2]-p1.x, d1 = v0[3]-p1.y;
      lwh += 0.5f*sc2*(d0*d0 + d1*d1);
      l2p += sc2*(d0*d0 + d1*d1);
      lobj += -clg(so0); l2p += (so0-1.f)*(so0-1.f);
      const int pos = atomicAdd((int*)ws + CNT_O, 1);
      if (pos < 1024){ ((int*)ws)[LIST_O + pos*2] = (bb*AD + a)*FFD + hw0;
                       ((int*)ws)[LIST_O + pos*2 + 1] = (int)p1.w; }
    } else if (!(mx0 > s7_0)){ lobj += -clg(1.f - so0); l2p += so0*so0; }
    // item 1
    if (ks1 >= 0){
      const f32x2 p0 = *(const f32x2*)&rb[ks1*16 + 6];
      const f32x4 p1 = *(const f32x4*)&rb[ks1*16 + 8];
      const float sc = p1.z, sc2 = sc*sc;
      lxy += sc2*(bce(sx1, p0.x) + bce(sy1, p0.y));
      l2p += (sx1-p0.x)*(sx1-p0.x) + (sy1-p0.y)*(sy1-p0.y);
      const float d0 = v1[2]-p1.x, d1 = v1[3]-p1.y;
      lwh += 0.5f*sc2*(d0*d0 + d1*d1);
      l2p += sc2*(d0*d0 + d1*d1);
      lobj += -clg(so1); l2p += (so1-1.f)*(so1-1.f);
      const int pos = atomicAdd((int*)ws + CNT_O, 1);
      if (pos < 1024){ ((int*)ws)[LIST_O + pos*2] = (bb*AD + a)*FFD + hw1;
                       ((int*)ws)[LIST_O + pos*2 + 1] = (int)p1.w; }
    } else if (!(mx1 > s7_1)){ lobj += -clg(1.f - so1); l2p += so1*so1; }
  }

  #pragma unroll
  for (int o = 32; o > 0; o >>= 1){
    lxy  += __shfl_down(lxy,  o, 64);
    lwh  += __shfl_down(lwh,  o, 64);
    lobj += __shfl_down(lobj, o, 64);
    l2p  += __shfl_down(l2p,  o, 64);
  }
  __syncthreads();
  if (lane == 0){
    lds[wv*4+0] = lxy; lds[wv*4+1] = lwh; lds[wv*4+2] = lobj; lds[wv*4+3] = l2p;
  }
  __syncthreads();
  if (tid < 4)
    ws[BLK_O + blockIdx.x*4 + tid] =
      lds[0*4+tid] + lds[1*4+tid] + lds[2*4+tid] + lds[3*4+tid];
}

// ---------------- cls kernel: 80 channels at matched cells only -----------------------
__global__ __launch_bounds__(128) void cls_kernel(const float* __restrict__ xin,
    const float* __restrict__ cw, const float* __restrict__ cb, float* __restrict__ ws){
  const int cnt = ((const int*)ws)[CNT_O];
  if ((int)blockIdx.x >= cnt) return;
  const int cA  = ((const int*)ws)[LIST_O + blockIdx.x*2];
  const int cls = ((const int*)ws)[LIST_O + blockIdx.x*2 + 1];
  const int b   = cA / (AD*FFD);
  const int rem = cA - b*AD*FFD;
  const int a   = rem / FFD;
  const int hw  = rem - a*FFD;
  __shared__ float xs[256];
  __shared__ float sm[128];
  const int tid = threadIdx.x;
  const float* xb = xin + ((size_t)b*CD)*FFD + hw;
  xs[tid]       = xb[(size_t)tid*FFD];
  xs[tid + 128] = xb[(size_t)(tid + 128)*FFD];
  __syncthreads();
  float lcls = 0.f, l2p = 0.f;
  if (tid < 80){
    const int o = a*85 + 5 + tid;
    const float* wr = cw + o*CD;
    float s = 0.f;
    #pragma unroll 8
    for (int c = 0; c < CD; ++c) s += xs[c]*wr[c];
    const float e = sigm(s + cb[o]);
    const float t = (tid == cls) ? 1.f : 0.f;
    lcls = bce(e, t);
    l2p  = (e - t)*(e - t);
  }
  sm[tid] = lcls; __syncthreads();
  for (int s2 = 64; s2 > 0; s2 >>= 1){ if (tid < s2) sm[tid] += sm[tid+s2]; __syncthreads(); }
  if (tid == 0) atomicAdd(ws + ACC_O + 3, sm[0]);
  __syncthreads();
  sm[tid] = l2p; __syncthreads();
  for (int s2 = 64; s2 > 0; s2 >>= 1){ if (tid < s2) sm[tid] += sm[tid+s2]; __syncthreads(); }
  if (tid == 0) atomicAdd(ws + ACC_O + 4, sm[0]);
}

// ---------------- finalize ------------------------------------------------------------
__global__ __launch_bounds__(256) void fin_kernel(const float* __restrict__ ws,
                                                  float* __restrict__ out){
  __shared__ float sm[256];
  const int tid = threadIdx.x;
  float p[4] = {0,0,0,0};
  for (int i = tid; i < NBLK; i += 256){
    p[0] += ws[BLK_O + i*4 + 0];
    p[1] += ws[BLK_O + i*4 + 1];
    p[2] += ws[BLK_O + i*4 + 2];
    p[3] += ws[BLK_O + i*4 + 3];
  }
  float tot[4];
  #pragma unroll
  for (int r = 0; r < 4; ++r){
    __syncthreads();
    sm[tid] = p[r];
    __syncthreads();
    for (int s = 128; s > 0; s >>= 1){
      if (tid < s) sm[tid] += sm[tid + s];
      __syncthreads();
    }
    tot[r] = sm[0];
  }
  if (tid == 0){
    const float lxy = tot[0], lwh = tot[1], lobj = tot[2];
    const float lcls = ws[ACC_O+3];
    const float l2   = tot[3] + ws[ACC_O+4];
    out[0] = lxy + lwh + lobj + lcls;
    out[1] = lxy; out[2] = lwh; out[3] = lobj; out[4] = lcls; out[5] = l2;
  }
}

extern "C" void kernel_launch(void* const* d_in, const int* in_sizes, int n_in,
                              void* d_out, int out_size, void* d_ws, size_t ws_size,
                              hipStream_t stream){
  const float* xin    = (const float*)d_in[0];
  const float* labels = (const float*)d_in[1];
  const float* cw     = (const float*)d_in[2];
  const float* cb     = (const float*)d_in[3];
  float* out = (float*)d_out;
  float* ws  = (float*)d_ws;

  label_kernel<<<4, 256, 0, stream>>>(labels, ws);
  fused_kernel<<<NBLK, 256, 0, stream>>>(xin, cw, cb, ws);
  cls_kernel<<<800, 128, 0, stream>>>(xin, cw, cb, ws);
  fin_kernel<<<1, 256, 0, stream>>>(ws, out);
}